// Round 1
// baseline (1722.763 us; speedup 1.0000x reference)
//
#include <hip/hip_runtime.h>

#define NB    8
#define NPTS  16384
#define NS    512
#define NK    64
#define C1    64
#define C2    128
#define RAD2  0.25f
#define MTOT  (NB*NS*NK)   // 262144 rows
// stats layout (floats) in ws after feat:
// [0:64) s0sum | [64:128) s0sq | [128:256) s1sum | [256:384) s1sq
// [384:448) bn0a | [448:512) bn0c | [512:640) bn1a | [640:768) bn1c

// ---------------- FPS: bit-exact farthest point sampling ----------------
__global__ __launch_bounds__(1024) void fps_kernel(const float* __restrict__ xyz,
                                                   float* __restrict__ out) {
    int b = blockIdx.x;
    int tid = threadIdx.x;
    const float* base = xyz + (size_t)b * NPTS * 3;
    float px[16], py[16], pz[16], dd[16];
#pragma unroll
    for (int j = 0; j < 16; ++j) {
        int p = tid + (j << 10);
        px[j] = base[p * 3 + 0];
        py[j] = base[p * 3 + 1];
        pz[j] = base[p * 3 + 2];
        dd[j] = 1e10f;
    }
    __shared__ float scx, scy, scz;
    __shared__ int sfar;
    __shared__ float swv[16];
    __shared__ int swi[16];
    if (tid == 0) sfar = 0;
    __syncthreads();
    for (int i = 0; i < NS; ++i) {
        int far = sfar;
        int ot = far & 1023, oj = far >> 10;
        if (tid == ot) {
            float x = px[oj], y = py[oj], z = pz[oj];
            scx = x; scy = y; scz = z;
            float* o = out + ((size_t)b * NS + i) * 3;
            o[0] = x; o[1] = y; o[2] = z;
        }
        __syncthreads();
        float cx = scx, cy = scy, cz = scz;
        float bv = -1.0f;
        int bi = 0;
#pragma unroll
        for (int j = 0; j < 16; ++j) {
            // bit-exact: rn ops, no contraction, sum order ((x+y)+z)
            float dx = __fsub_rn(px[j], cx);
            float dy = __fsub_rn(py[j], cy);
            float dz = __fsub_rn(pz[j], cz);
            float d = __fadd_rn(__fadd_rn(__fmul_rn(dx, dx), __fmul_rn(dy, dy)),
                                __fmul_rn(dz, dz));
            float nd = fminf(dd[j], d);
            dd[j] = nd;
            if (nd > bv) { bv = nd; bi = tid + (j << 10); }  // strict > keeps lowest idx
        }
        // wave (64) argmax reduce, tie-break min index
#pragma unroll
        for (int off = 32; off >= 1; off >>= 1) {
            float ov = __shfl_xor(bv, off);
            int oi = __shfl_xor(bi, off);
            if (ov > bv || (ov == bv && oi < bi)) { bv = ov; bi = oi; }
        }
        int w = tid >> 6;
        if ((tid & 63) == 0) { swv[w] = bv; swi[w] = bi; }
        __syncthreads();
        if (tid < 64) {
            float v = (tid < 16) ? swv[tid] : -1.0f;
            int ii = (tid < 16) ? swi[tid] : 0x7fffffff;
#pragma unroll
            for (int off = 8; off >= 1; off >>= 1) {
                float ov = __shfl_xor(v, off);
                int oi = __shfl_xor(ii, off);
                if (ov > v || (ov == v && oi < ii)) { v = ov; ii = oi; }
            }
            if (tid == 0) sfar = ii;
        }
        __syncthreads();
    }
}

// ------------- Ball query (exact expanded-form distance) + gather -------------
__global__ __launch_bounds__(256) void ballq_kernel(const float* __restrict__ xyz,
                                                    const float* __restrict__ pts,
                                                    const float* __restrict__ newxyz,
                                                    float* __restrict__ feat) {
    int w = threadIdx.x >> 6;
    int lane = threadIdx.x & 63;
    int wid = blockIdx.x * 4 + w;   // 0..4095 == b*512+s
    int b = wid >> 9;
    const float* nx = newxyz + (size_t)wid * 3;
    float cx = nx[0], cy = nx[1], cz = nx[2];
    float sa = __fadd_rn(__fadd_rn(__fmul_rn(cx, cx), __fmul_rn(cy, cy)),
                         __fmul_rn(cz, cz));
    __shared__ int sidx[4][64];
    const float* base = xyz + (size_t)b * NPTS * 3;
    int cnt = 0;
    for (int off = 0; off < NPTS && cnt < NK; off += 64) {
        int p = off + lane;
        float bx = base[p * 3 + 0], by = base[p * 3 + 1], bz = base[p * 3 + 2];
        float sb = __fadd_rn(__fadd_rn(__fmul_rn(bx, bx), __fmul_rn(by, by)),
                             __fmul_rn(bz, bz));
        float dt = __fadd_rn(__fadd_rn(__fmul_rn(cx, bx), __fmul_rn(cy, by)),
                             __fmul_rn(cz, bz));
        float sq = __fsub_rn(__fadd_rn(sa, sb), __fmul_rn(2.0f, dt));
        bool inb = !(sq > RAD2);           // strict >, matches reference
        unsigned long long mask = __ballot(inb);
        int pos = cnt + (int)__popcll(mask & ((1ull << lane) - 1ull));
        if (inb && pos < NK) sidx[w][pos] = p;
        cnt += (int)__popcll(mask);
    }
    __syncthreads();
    int filled = cnt < NK ? cnt : NK;
    int sel = (lane < filled) ? lane : 0;
    int p = (filled > 0) ? sidx[w][sel] : 0;  // filled>0 always (self in radius)
    float gx = base[p * 3 + 0], gy = base[p * 3 + 1], gz = base[p * 3 + 2];
    const float* pb = pts + (size_t)b * NPTS * 3;
    float q0 = pb[p * 3 + 0], q1 = pb[p * 3 + 1], q2 = pb[p * 3 + 2];
    float* fr = feat + ((size_t)wid * NK + lane) * 6;
    fr[0] = __fsub_rn(gx, cx);
    fr[1] = __fsub_rn(gy, cy);
    fr[2] = __fsub_rn(gz, cz);
    fr[3] = q0; fr[4] = q1; fr[5] = q2;
}

// ---------------- Layer-0 stats: per-channel sum/sumsq of h0raw ----------------
__global__ __launch_bounds__(256) void stats0_kernel(const float* __restrict__ feat,
                                                     const float* __restrict__ W0,
                                                     const float* __restrict__ b0,
                                                     float* __restrict__ stats) {
    int lane = threadIdx.x & 63;
    int wid = blockIdx.x * 4 + (threadIdx.x >> 6);  // 0..1023
    float w0[6];
#pragma unroll
    for (int j = 0; j < 6; ++j) w0[j] = W0[lane * 6 + j];
    float bb = b0[lane];
    float ssum = 0.f, ssq = 0.f;
    int r0 = wid * 256;
    for (int r = r0; r < r0 + 256; ++r) {
        const float* f = feat + (size_t)r * 6;
        float h = bb;
#pragma unroll
        for (int j = 0; j < 6; ++j) h = fmaf(w0[j], f[j], h);
        ssum += h;
        ssq = fmaf(h, h, ssq);
    }
    atomicAdd(&stats[lane], ssum);
    atomicAdd(&stats[64 + lane], ssq);
}

__global__ void fin0_kernel(const float* __restrict__ g0, const float* __restrict__ be0,
                            float* __restrict__ stats) {
    int c = threadIdx.x;  // 64 threads
    const float inv = 1.0f / (float)MTOT;  // 2^-18, exact
    float mu = stats[c] * inv;
    float var = fmaxf(stats[64 + c] * inv - mu * mu, 0.f);
    float a = g0[c] * rsqrtf(var + 1e-5f);
    stats[384 + c] = a;
    stats[448 + c] = fmaf(-mu, a, be0[c]);
}

// ---------------- Layer-1 stats: recompute h0n -> h1raw, sum/sumsq ----------------
__global__ __launch_bounds__(256) void stats1_kernel(const float* __restrict__ feat,
                                                     const float* __restrict__ W0,
                                                     const float* __restrict__ b0,
                                                     const float* __restrict__ W1,
                                                     const float* __restrict__ b1,
                                                     float* __restrict__ stats) {
    int lane = threadIdx.x & 63;
    int w = threadIdx.x >> 6;
    int half = w & 1;
    int pairG = blockIdx.x * 2 + (w >> 1);  // 0..2047
    int ch = half * 64 + lane;
    float w0r[6];
#pragma unroll
    for (int j = 0; j < 6; ++j) w0r[j] = W0[lane * 6 + j];
    float b0v = b0[lane];
    float a0 = stats[384 + lane], c0 = stats[448 + lane];
    float w1r[64];
#pragma unroll
    for (int j = 0; j < 64; ++j) w1r[j] = W1[ch * 64 + j];
    float b1v = b1[ch];
    float ssum = 0.f, ssq = 0.f;
    int r0 = pairG * 128;
    for (int r = r0; r < r0 + 128; ++r) {
        const float* f = feat + (size_t)r * 6;
        float h = b0v;
#pragma unroll
        for (int j = 0; j < 6; ++j) h = fmaf(w0r[j], f[j], h);
        float h0n = fmaxf(fmaf(a0, h, c0), 0.f);
        int hbits = __float_as_int(h0n);
        float a0c = 0.f, a1c = 0.f, a2c = 0.f, a3c = 0.f;
#pragma unroll
        for (int j = 0; j < 64; j += 4) {
            a0c = fmaf(w1r[j + 0], __int_as_float(__builtin_amdgcn_readlane(hbits, j + 0)), a0c);
            a1c = fmaf(w1r[j + 1], __int_as_float(__builtin_amdgcn_readlane(hbits, j + 1)), a1c);
            a2c = fmaf(w1r[j + 2], __int_as_float(__builtin_amdgcn_readlane(hbits, j + 2)), a2c);
            a3c = fmaf(w1r[j + 3], __int_as_float(__builtin_amdgcn_readlane(hbits, j + 3)), a3c);
        }
        float acc = b1v + ((a0c + a1c) + (a2c + a3c));
        ssum += acc;
        ssq = fmaf(acc, acc, ssq);
    }
    atomicAdd(&stats[128 + ch], ssum);
    atomicAdd(&stats[256 + ch], ssq);
}

__global__ void fin1_kernel(const float* __restrict__ g1, const float* __restrict__ be1,
                            float* __restrict__ stats) {
    int c = threadIdx.x;  // 128 threads
    const float inv = 1.0f / (float)MTOT;
    float mu = stats[128 + c] * inv;
    float var = fmaxf(stats[256 + c] * inv - mu * mu, 0.f);
    float a = g1[c] * rsqrtf(var + 1e-5f);
    stats[512 + c] = a;
    stats[640 + c] = fmaf(-mu, a, be1[c]);
}

// ---------------- Final: recompute h1n, max over K, write output ----------------
__global__ __launch_bounds__(256) void final_kernel(const float* __restrict__ feat,
                                                    const float* __restrict__ W0,
                                                    const float* __restrict__ b0,
                                                    const float* __restrict__ W1,
                                                    const float* __restrict__ b1,
                                                    const float* __restrict__ stats,
                                                    float* __restrict__ out) {
    int lane = threadIdx.x & 63;
    int w = threadIdx.x >> 6;
    int half = w & 1;
    int g = blockIdx.x * 2 + (w >> 1);  // 0..4095 == b*512+s
    int ch = half * 64 + lane;
    float w0r[6];
#pragma unroll
    for (int j = 0; j < 6; ++j) w0r[j] = W0[lane * 6 + j];
    float b0v = b0[lane];
    float a0 = stats[384 + lane], c0 = stats[448 + lane];
    float w1r[64];
#pragma unroll
    for (int j = 0; j < 64; ++j) w1r[j] = W1[ch * 64 + j];
    float b1v = b1[ch];
    float a1 = stats[512 + ch], c1 = stats[640 + ch];
    float mx = -1e30f;
    int r0 = g * 64;
    for (int k = 0; k < 64; ++k) {
        const float* f = feat + (size_t)(r0 + k) * 6;
        float h = b0v;
#pragma unroll
        for (int j = 0; j < 6; ++j) h = fmaf(w0r[j], f[j], h);
        float h0n = fmaxf(fmaf(a0, h, c0), 0.f);
        int hbits = __float_as_int(h0n);
        float a0c = 0.f, a1c = 0.f, a2c = 0.f, a3c = 0.f;
#pragma unroll
        for (int j = 0; j < 64; j += 4) {
            a0c = fmaf(w1r[j + 0], __int_as_float(__builtin_amdgcn_readlane(hbits, j + 0)), a0c);
            a1c = fmaf(w1r[j + 1], __int_as_float(__builtin_amdgcn_readlane(hbits, j + 1)), a1c);
            a2c = fmaf(w1r[j + 2], __int_as_float(__builtin_amdgcn_readlane(hbits, j + 2)), a2c);
            a3c = fmaf(w1r[j + 3], __int_as_float(__builtin_amdgcn_readlane(hbits, j + 3)), a3c);
        }
        float acc = b1v + ((a0c + a1c) + (a2c + a3c));
        float h1n = fmaxf(fmaf(a1, acc, c1), 0.f);
        mx = fmaxf(mx, h1n);
    }
    out[12288 + (size_t)g * 128 + ch] = mx;
}

extern "C" void kernel_launch(void* const* d_in, const int* in_sizes, int n_in,
                              void* d_out, int out_size, void* d_ws, size_t ws_size,
                              hipStream_t stream) {
    const float* xyz = (const float*)d_in[0];
    const float* pts = (const float*)d_in[1];
    const float* W0  = (const float*)d_in[2];
    const float* b0  = (const float*)d_in[3];
    const float* g0  = (const float*)d_in[4];
    const float* be0 = (const float*)d_in[5];
    const float* W1  = (const float*)d_in[6];
    const float* b1  = (const float*)d_in[7];
    const float* g1  = (const float*)d_in[8];
    const float* be1 = (const float*)d_in[9];
    float* out = (float*)d_out;

    float* feat  = (float*)d_ws;                     // 262144*6 floats = 6.29 MB
    float* stats = feat + (size_t)MTOT * 6;          // 768 floats

    hipMemsetAsync(stats, 0, 384 * sizeof(float), stream);
    fps_kernel<<<NB, 1024, 0, stream>>>(xyz, out);
    ballq_kernel<<<1024, 256, 0, stream>>>(xyz, pts, out, feat);
    stats0_kernel<<<256, 256, 0, stream>>>(feat, W0, b0, stats);
    fin0_kernel<<<1, 64, 0, stream>>>(g0, be0, stats);
    stats1_kernel<<<1024, 256, 0, stream>>>(feat, W0, b0, W1, b1, stats);
    fin1_kernel<<<1, 128, 0, stream>>>(g1, be1, stats);
    final_kernel<<<2048, 256, 0, stream>>>(feat, W0, b0, W1, b1, stats, out);
}

// Round 2
// 1609.579 us; speedup vs baseline: 1.0703x; 1.0703x over previous
//
#include <hip/hip_runtime.h>

#define NB    8
#define NPTS  16384
#define NS    512
#define NK    64
#define C1    64
#define C2    128
#define RAD2  0.25f
#define MTOT  (NB*NS*NK)   // 262144 rows
// stats layout (floats) in ws after feat:
// [0:64) s0sum | [64:128) s0sq | [128:256) s1sum | [256:384) s1sq
// [384:448) bn0a | [448:512) bn0c | [512:640) bn1a | [640:768) bn1c

// ---------------- FPS: bit-exact farthest point sampling ----------------
// 512 threads x 32 points each, 2 barriers/iter, 511 update iterations.
__global__ __launch_bounds__(512, 2) void fps_kernel(const float* __restrict__ xyz,
                                                     float* __restrict__ out) {
    int b = blockIdx.x;
    int tid = threadIdx.x;
    int lane = tid & 63;
    int w = tid >> 6;  // 8 waves
    const float* base = xyz + (size_t)b * NPTS * 3;
    float px[32], py[32], pz[32], dd[32];
#pragma unroll
    for (int j = 0; j < 32; ++j) {
        int p = tid + (j << 9);
        px[j] = base[p * 3 + 0];
        py[j] = base[p * 3 + 1];
        pz[j] = base[p * 3 + 2];
        dd[j] = 1e10f;
    }
    __shared__ float sc[3];
    __shared__ float swv[8];
    __shared__ int swi[8];
    if (tid == 0) {
        sc[0] = px[0]; sc[1] = py[0]; sc[2] = pz[0];
        float* o = out + (size_t)b * NS * 3;
        o[0] = px[0]; o[1] = py[0]; o[2] = pz[0];
    }
    __syncthreads();
    for (int i = 1; i < NS; ++i) {
        float cx = sc[0], cy = sc[1], cz = sc[2];
        // 4 independent select chains to break the cmp->cndmask dependency
        float bvA[4] = {-1.f, -1.f, -1.f, -1.f};
        int biA[4] = {0, 0, 0, 0};
#pragma unroll
        for (int j = 0; j < 32; ++j) {
            // bit-exact: rn ops, no contraction, sum order ((x+y)+z)
            float dx = __fsub_rn(px[j], cx);
            float dy = __fsub_rn(py[j], cy);
            float dz = __fsub_rn(pz[j], cz);
            float d = __fadd_rn(__fadd_rn(__fmul_rn(dx, dx), __fmul_rn(dy, dy)),
                                __fmul_rn(dz, dz));
            float nd = fminf(dd[j], d);
            dd[j] = nd;
            int c = j & 3;
            if (nd > bvA[c]) { bvA[c] = nd; biA[c] = tid + (j << 9); }  // strict >: lowest j wins in-chain
        }
        float bv = bvA[0];
        int bi = biA[0];
#pragma unroll
        for (int c = 1; c < 4; ++c)
            if (bvA[c] > bv || (bvA[c] == bv && biA[c] < bi)) { bv = bvA[c]; bi = biA[c]; }
        // wave (64) argmax reduce, tie-break min index
#pragma unroll
        for (int off = 32; off >= 1; off >>= 1) {
            float ov = __shfl_xor(bv, off);
            int oi = __shfl_xor(bi, off);
            if (ov > bv || (ov == bv && oi < bi)) { bv = ov; bi = oi; }
        }
        if (lane == 0) { swv[w] = bv; swi[w] = bi; }
        __syncthreads();
        if (w == 0) {
            float v = (lane < 8) ? swv[lane] : -1e30f;
            int ii = (lane < 8) ? swi[lane] : 0x7fffffff;
#pragma unroll
            for (int off = 4; off >= 1; off >>= 1) {
                float ov = __shfl_xor(v, off);
                int oi = __shfl_xor(ii, off);
                if (ov > v || (ov == v && oi < ii)) { v = ov; ii = oi; }
            }
            // lanes 0-2 all hold the winner; fetch coords from L2 (no 3rd barrier)
            if (lane < 3) {
                float c = base[(size_t)ii * 3 + lane];
                sc[lane] = c;
                out[((size_t)b * NS + i) * 3 + lane] = c;
            }
        }
        __syncthreads();
    }
}

// ------------- Ball query (exact expanded-form distance) + gather -------------
__global__ __launch_bounds__(256) void ballq_kernel(const float* __restrict__ xyz,
                                                    const float* __restrict__ pts,
                                                    const float* __restrict__ newxyz,
                                                    float* __restrict__ feat) {
    int w = threadIdx.x >> 6;
    int lane = threadIdx.x & 63;
    int wid = blockIdx.x * 4 + w;   // 0..4095 == b*512+s
    int b = wid >> 9;
    const float* nx = newxyz + (size_t)wid * 3;
    float cx = nx[0], cy = nx[1], cz = nx[2];
    float sa = __fadd_rn(__fadd_rn(__fmul_rn(cx, cx), __fmul_rn(cy, cy)),
                         __fmul_rn(cz, cz));
    __shared__ int sidx[4][64];
    const float* base = xyz + (size_t)b * NPTS * 3;
    int cnt = 0;
    for (int off = 0; off < NPTS && cnt < NK; off += 64) {
        int p = off + lane;
        float bx = base[p * 3 + 0], by = base[p * 3 + 1], bz = base[p * 3 + 2];
        float sb = __fadd_rn(__fadd_rn(__fmul_rn(bx, bx), __fmul_rn(by, by)),
                             __fmul_rn(bz, bz));
        float dt = __fadd_rn(__fadd_rn(__fmul_rn(cx, bx), __fmul_rn(cy, by)),
                             __fmul_rn(cz, bz));
        float sq = __fsub_rn(__fadd_rn(sa, sb), __fmul_rn(2.0f, dt));
        bool inb = !(sq > RAD2);           // strict >, matches reference
        unsigned long long mask = __ballot(inb);
        int pos = cnt + (int)__popcll(mask & ((1ull << lane) - 1ull));
        if (inb && pos < NK) sidx[w][pos] = p;
        cnt += (int)__popcll(mask);
    }
    __syncthreads();
    int filled = cnt < NK ? cnt : NK;
    int sel = (lane < filled) ? lane : 0;
    int p = (filled > 0) ? sidx[w][sel] : 0;  // filled>0 always (self in radius)
    float gx = base[p * 3 + 0], gy = base[p * 3 + 1], gz = base[p * 3 + 2];
    const float* pb = pts + (size_t)b * NPTS * 3;
    float q0 = pb[p * 3 + 0], q1 = pb[p * 3 + 1], q2 = pb[p * 3 + 2];
    float* fr = feat + ((size_t)wid * NK + lane) * 6;
    fr[0] = __fsub_rn(gx, cx);
    fr[1] = __fsub_rn(gy, cy);
    fr[2] = __fsub_rn(gz, cz);
    fr[3] = q0; fr[4] = q1; fr[5] = q2;
}

// ---------------- Layer-0 stats: per-channel sum/sumsq of h0raw ----------------
__global__ __launch_bounds__(256) void stats0_kernel(const float* __restrict__ feat,
                                                     const float* __restrict__ W0,
                                                     const float* __restrict__ b0,
                                                     float* __restrict__ stats) {
    int lane = threadIdx.x & 63;
    int wid = blockIdx.x * 4 + (threadIdx.x >> 6);  // 0..1023
    float w0[6];
#pragma unroll
    for (int j = 0; j < 6; ++j) w0[j] = W0[lane * 6 + j];
    float bb = b0[lane];
    float ssum = 0.f, ssq = 0.f;
    int r0 = wid * 256;
    for (int r = r0; r < r0 + 256; ++r) {
        const float* f = feat + (size_t)r * 6;
        float h = bb;
#pragma unroll
        for (int j = 0; j < 6; ++j) h = fmaf(w0[j], f[j], h);
        ssum += h;
        ssq = fmaf(h, h, ssq);
    }
    atomicAdd(&stats[lane], ssum);
    atomicAdd(&stats[64 + lane], ssq);
}

__global__ void fin0_kernel(const float* __restrict__ g0, const float* __restrict__ be0,
                            float* __restrict__ stats) {
    int c = threadIdx.x;  // 64 threads
    const float inv = 1.0f / (float)MTOT;  // 2^-18, exact
    float mu = stats[c] * inv;
    float var = fmaxf(stats[64 + c] * inv - mu * mu, 0.f);
    float a = g0[c] * rsqrtf(var + 1e-5f);
    stats[384 + c] = a;
    stats[448 + c] = fmaf(-mu, a, be0[c]);
}

// ---------------- Layer-1 stats: recompute h0n -> h1raw, sum/sumsq ----------------
__global__ __launch_bounds__(256) void stats1_kernel(const float* __restrict__ feat,
                                                     const float* __restrict__ W0,
                                                     const float* __restrict__ b0,
                                                     const float* __restrict__ W1,
                                                     const float* __restrict__ b1,
                                                     float* __restrict__ stats) {
    int lane = threadIdx.x & 63;
    int w = threadIdx.x >> 6;
    int half = w & 1;
    int pairG = blockIdx.x * 2 + (w >> 1);  // 0..2047
    int ch = half * 64 + lane;
    float w0r[6];
#pragma unroll
    for (int j = 0; j < 6; ++j) w0r[j] = W0[lane * 6 + j];
    float b0v = b0[lane];
    float a0 = stats[384 + lane], c0 = stats[448 + lane];
    float w1r[64];
#pragma unroll
    for (int j = 0; j < 64; ++j) w1r[j] = W1[ch * 64 + j];
    float b1v = b1[ch];
    float ssum = 0.f, ssq = 0.f;
    int r0 = pairG * 128;
    for (int r = r0; r < r0 + 128; ++r) {
        const float* f = feat + (size_t)r * 6;
        float h = b0v;
#pragma unroll
        for (int j = 0; j < 6; ++j) h = fmaf(w0r[j], f[j], h);
        float h0n = fmaxf(fmaf(a0, h, c0), 0.f);
        int hbits = __float_as_int(h0n);
        float a0c = 0.f, a1c = 0.f, a2c = 0.f, a3c = 0.f;
#pragma unroll
        for (int j = 0; j < 64; j += 4) {
            a0c = fmaf(w1r[j + 0], __int_as_float(__builtin_amdgcn_readlane(hbits, j + 0)), a0c);
            a1c = fmaf(w1r[j + 1], __int_as_float(__builtin_amdgcn_readlane(hbits, j + 1)), a1c);
            a2c = fmaf(w1r[j + 2], __int_as_float(__builtin_amdgcn_readlane(hbits, j + 2)), a2c);
            a3c = fmaf(w1r[j + 3], __int_as_float(__builtin_amdgcn_readlane(hbits, j + 3)), a3c);
        }
        float acc = b1v + ((a0c + a1c) + (a2c + a3c));
        ssum += acc;
        ssq = fmaf(acc, acc, ssq);
    }
    atomicAdd(&stats[128 + ch], ssum);
    atomicAdd(&stats[256 + ch], ssq);
}

__global__ void fin1_kernel(const float* __restrict__ g1, const float* __restrict__ be1,
                            float* __restrict__ stats) {
    int c = threadIdx.x;  // 128 threads
    const float inv = 1.0f / (float)MTOT;
    float mu = stats[128 + c] * inv;
    float var = fmaxf(stats[256 + c] * inv - mu * mu, 0.f);
    float a = g1[c] * rsqrtf(var + 1e-5f);
    stats[512 + c] = a;
    stats[640 + c] = fmaf(-mu, a, be1[c]);
}

// ---------------- Final: recompute h1n, max over K, write output ----------------
__global__ __launch_bounds__(256) void final_kernel(const float* __restrict__ feat,
                                                    const float* __restrict__ W0,
                                                    const float* __restrict__ b0,
                                                    const float* __restrict__ W1,
                                                    const float* __restrict__ b1,
                                                    const float* __restrict__ stats,
                                                    float* __restrict__ out) {
    int lane = threadIdx.x & 63;
    int w = threadIdx.x >> 6;
    int half = w & 1;
    int g = blockIdx.x * 2 + (w >> 1);  // 0..4095 == b*512+s
    int ch = half * 64 + lane;
    float w0r[6];
#pragma unroll
    for (int j = 0; j < 6; ++j) w0r[j] = W0[lane * 6 + j];
    float b0v = b0[lane];
    float a0 = stats[384 + lane], c0 = stats[448 + lane];
    float w1r[64];
#pragma unroll
    for (int j = 0; j < 64; ++j) w1r[j] = W1[ch * 64 + j];
    float b1v = b1[ch];
    float a1 = stats[512 + ch], c1 = stats[640 + ch];
    float mx = -1e30f;
    int r0 = g * 64;
    for (int k = 0; k < 64; ++k) {
        const float* f = feat + (size_t)(r0 + k) * 6;
        float h = b0v;
#pragma unroll
        for (int j = 0; j < 6; ++j) h = fmaf(w0r[j], f[j], h);
        float h0n = fmaxf(fmaf(a0, h, c0), 0.f);
        int hbits = __float_as_int(h0n);
        float a0c = 0.f, a1c = 0.f, a2c = 0.f, a3c = 0.f;
#pragma unroll
        for (int j = 0; j < 64; j += 4) {
            a0c = fmaf(w1r[j + 0], __int_as_float(__builtin_amdgcn_readlane(hbits, j + 0)), a0c);
            a1c = fmaf(w1r[j + 1], __int_as_float(__builtin_amdgcn_readlane(hbits, j + 1)), a1c);
            a2c = fmaf(w1r[j + 2], __int_as_float(__builtin_amdgcn_readlane(hbits, j + 2)), a2c);
            a3c = fmaf(w1r[j + 3], __int_as_float(__builtin_amdgcn_readlane(hbits, j + 3)), a3c);
        }
        float acc = b1v + ((a0c + a1c) + (a2c + a3c));
        float h1n = fmaxf(fmaf(a1, acc, c1), 0.f);
        mx = fmaxf(mx, h1n);
    }
    out[12288 + (size_t)g * 128 + ch] = mx;
}

extern "C" void kernel_launch(void* const* d_in, const int* in_sizes, int n_in,
                              void* d_out, int out_size, void* d_ws, size_t ws_size,
                              hipStream_t stream) {
    const float* xyz = (const float*)d_in[0];
    const float* pts = (const float*)d_in[1];
    const float* W0  = (const float*)d_in[2];
    const float* b0  = (const float*)d_in[3];
    const float* g0  = (const float*)d_in[4];
    const float* be0 = (const float*)d_in[5];
    const float* W1  = (const float*)d_in[6];
    const float* b1  = (const float*)d_in[7];
    const float* g1  = (const float*)d_in[8];
    const float* be1 = (const float*)d_in[9];
    float* out = (float*)d_out;

    float* feat  = (float*)d_ws;                     // 262144*6 floats = 6.29 MB
    float* stats = feat + (size_t)MTOT * 6;          // 768 floats

    hipMemsetAsync(stats, 0, 384 * sizeof(float), stream);
    fps_kernel<<<NB, 512, 0, stream>>>(xyz, out);
    ballq_kernel<<<1024, 256, 0, stream>>>(xyz, pts, out, feat);
    stats0_kernel<<<256, 256, 0, stream>>>(feat, W0, b0, stats);
    fin0_kernel<<<1, 64, 0, stream>>>(g0, be0, stats);
    stats1_kernel<<<1024, 256, 0, stream>>>(feat, W0, b0, W1, b1, stats);
    fin1_kernel<<<1, 128, 0, stream>>>(g1, be1, stats);
    final_kernel<<<2048, 256, 0, stream>>>(feat, W0, b0, W1, b1, stats, out);
}